// Round 9
// baseline (383.589 us; speedup 1.0000x reference)
//
#include <hip/hip_runtime.h>
#include <hip/hip_bf16.h>

// Dipole: day-emb GEMM -> fwd GRU + 64 reverse GRUs -> masked softmax attention -> 2-layer head.
// T=64 B=32 D_IN=4096 D_DAY=H=256 D_OUT=942.
//
//  k1 pack_misc     : bf16 weight-frag packing + x->bf16 + Whh int8 frags + combined bias.
//  k2 gemm_k<0>     : day_emb = xb @ W_emb^T + b_emb      (M=32, grid (64,4), B-dbuf)
//  k3 gemm_git      : Git = day_emb @ Wih^T + bias        (M=64 + transpose epilogue ->
//                     Git[dir][t][g][bh][d][b16]; B-dbuf added vs R6)
//  k4 gru_recurrent : EXACT R5 kernel (measured best 118.5us). R7/R8 lessons: 8 waves exposes
//                     the latency ladder; per-step scattered global stores enter the in-order
//                     vmcnt retirement chain. R5's hist LDS + batched b128 flush avoids both.
//  k5 attn          : per-(i,b) wave online softmax -> ht = [c_f|c_r|fwd|rev_last]
//  k6 head_fused    : out = sigmoid((ht @ W_ao^T + b_ao) @ W_o^T + b_o) -- one kernel,
//                     intermediate 32x256 tile lives in LDS (saves launch + tmp roundtrip,
//                     ht read 1x instead of 4x).

typedef __bf16 bf16x8 __attribute__((ext_vector_type(8)));
typedef __bf16 bf16x4 __attribute__((ext_vector_type(4)));
typedef float  f32x4  __attribute__((ext_vector_type(4)));
typedef int    int4v  __attribute__((ext_vector_type(4)));

static constexpr float NEG_L2E = -1.442695041f;   // -log2(e)
static constexpr float TWO_L2E =  2.885390082f;   //  2*log2(e)

// ---------------- workspace layout (bytes) ----------------
static constexpr size_t OFF_PK_EMB = 0;                        // 256x4096 bf16    = 2097152
static constexpr size_t OFF_PK_IH  = 2097152;                  // 1536x256 bf16    =  786432
static constexpr size_t OFF_WQ     = 2883584;                  // 2x768x256 int8   =  393216
static constexpr size_t OFF_WSC    = 3276800;                  // 1536 f32         =    6144
static constexpr size_t OFF_PK_AO  = 3670016;                  // 256x1024 bf16    =  524288
static constexpr size_t OFF_PK_O   = 4194304;                  // 960x256 bf16     =  491520
static constexpr size_t OFF_DAY    = 4685824;                  // 2048x256 bf16    = 1048576
static constexpr size_t OFF_GIT    = 5734400;                  // 2*64*3*2*256*16 bf16 = 6291456
static constexpr size_t OFF_BC     = 12025856;                 // 1536 f32         =    6144
static constexpr size_t OFF_REV    = 18317312;                 // 2080*32*256 bf16 = 34078720
static constexpr size_t OFF_FWD    = 52396032;                 // 64*32*256 bf16   = 1048576
static constexpr size_t OFF_HT     = 53444608;                 // 2048x1024 bf16   = 4194304
// xb (2048x4096 bf16 = 16.7MB) aliases OFF_REV: dead before gru_recurrent writes rev.
static constexpr size_t OFF_XB     = OFF_REV;

__device__ __forceinline__ float sigf(float x) {
    return __builtin_amdgcn_rcpf(1.f + __expf(-x));
}

// lgkmcnt-only barrier: does NOT drain vmcnt.
#define LDS_BARRIER() asm volatile("s_waitcnt lgkmcnt(0)\n\ts_barrier" ::: "memory")

// ---------------- fused packer: bf16 frags + x->bf16 + Whh int8 + bias ----------------
// bf16 frag layout: flat = ((nt*K32+ks)*64+lane)*8+j holds W[nt*16+lane%16][ks*32+(lane/16)*8+j]
// i8 frag (A/B lane-symmetric): (n,k): lane=(n&15)|(((k>>4)&3)<<4), byte j=k&15;
//   flat = dir*196608 + ((n>>4)*4 + (k>>6))*1024 + lane*16 + j.
__global__ __launch_bounds__(256) void pack_misc(
    const float* __restrict__ We,  const float* __restrict__ Wir, const float* __restrict__ Wif,
    const float* __restrict__ Wao, const float* __restrict__ Wo,  const float* __restrict__ x,
    const float* __restrict__ Whr, const float* __restrict__ Whf,
    const float* __restrict__ bih_r, const float* __restrict__ bih_f,
    const float* __restrict__ bhh_r, const float* __restrict__ bhh_f,
    __bf16* pe, __bf16* pi, __bf16* pao, __bf16* po, __bf16* xb,
    signed char* __restrict__ wq, float* __restrict__ wscale, float* __restrict__ bc)
{
    int b = blockIdx.x;
    if (b >= 5048) {                      // Whh int8 pack: 4 rows per block (one per wave)
        int rowb = (b - 5048) * 4 + (threadIdx.x >> 6);   // 0..1535: dir*768 + n
        int t = threadIdx.x & 63;
        int dir = (rowb >= 768) ? 1 : 0;
        int n = rowb - dir * 768;
        const float* src = (dir ? Whf : Whr) + (size_t)n * 256;
        float4 wv = ((const float4*)src)[t];
        float m = fmaxf(fmaxf(fabsf(wv.x), fabsf(wv.y)), fmaxf(fabsf(wv.z), fabsf(wv.w)));
#pragma unroll
        for (int off = 32; off > 0; off >>= 1) m = fmaxf(m, __shfl_xor(m, off));
        m = fmaxf(m, 1e-20f);
        float inv = 127.f / m;
        int q0 = (int)__builtin_rintf(wv.x * inv);
        int q1 = (int)__builtin_rintf(wv.y * inv);
        int q2 = (int)__builtin_rintf(wv.z * inv);
        int q3 = (int)__builtin_rintf(wv.w * inv);
        int pk = (q0 & 0xff) | ((q1 & 0xff) << 8) | ((q2 & 0xff) << 16) | ((q3 & 0xff) << 24);
        int dlane = (n & 15) | (((t >> 2) & 3) << 4);
        size_t byte = (size_t)dir * 196608 + ((size_t)(n >> 4) * 4 + (t >> 4)) * 1024
                    + (size_t)dlane * 16 + (t & 3) * 4;
        *(int*)(wq + byte) = pk;
        if (t == 0) {
            float gc = (n < 512) ? NEG_L2E : TWO_L2E;
            wscale[rowb] = m * (1.f / 16129.f) * gc;
            const float* bi = dir ? bih_f : bih_r;
            const float* bh = dir ? bhh_f : bhh_r;
            bc[rowb] = (n < 512) ? (bi[n] + bh[n]) * NEG_L2E : bi[n] * TWO_L2E;
        }
        return;
    }
    if (b >= 952) {                       // x -> bf16 (8 elems/thread)
        size_t base = ((size_t)(b - 952) * 256 + threadIdx.x) * 8;
        float4 v0 = *(const float4*)(x + base);
        float4 v1 = *(const float4*)(x + base + 4);
        bf16x8 o;
        o[0]=(__bf16)v0.x; o[1]=(__bf16)v0.y; o[2]=(__bf16)v0.z; o[3]=(__bf16)v0.w;
        o[4]=(__bf16)v1.x; o[5]=(__bf16)v1.y; o[6]=(__bf16)v1.z; o[7]=(__bf16)v1.w;
        *(bf16x8*)(xb + base) = o;
        return;
    }
    const float* src; __bf16* dst; int Nsrc, k32l, b0; bool ih = false;
    if (b < 512)      { src = We;  dst = pe;          Nsrc = 256; k32l = 7; b0 = 0;   }
    else if (b < 608) { src = Wir; dst = pi;          Nsrc = 768; k32l = 3; b0 = 512; ih = true; }
    else if (b < 704) { src = Wif; dst = pi + 196608; Nsrc = 768; k32l = 3; b0 = 608; ih = true; }
    else if (b < 832) { src = Wao; dst = pao;         Nsrc = 256; k32l = 5; b0 = 704; }
    else              { src = Wo;  dst = po;          Nsrc = 942; k32l = 3; b0 = 832; }
    int t8   = (b - b0) * 256 + threadIdx.x;
    int lane = t8 & 63;
    int K32  = 1 << k32l;
    int K    = K32 << 5;
    int ks   = (t8 >> 6) & (K32 - 1);
    int nt   = t8 >> (6 + k32l);
    int n    = nt * 16 + (lane & 15);
    int k0   = ks * 32 + ((lane >> 4) << 3);
    bf16x8 o;
    if (n < Nsrc) {
        const float* sp = src + (size_t)n * K + k0;
        float4 v0 = *(const float4*)sp;
        float4 v1 = *(const float4*)(sp + 4);
        float s = ih ? ((n < 512) ? NEG_L2E : TWO_L2E) : 1.f;
        o[0]=(__bf16)(v0.x*s); o[1]=(__bf16)(v0.y*s); o[2]=(__bf16)(v0.z*s); o[3]=(__bf16)(v0.w*s);
        o[4]=(__bf16)(v1.x*s); o[5]=(__bf16)(v1.y*s); o[6]=(__bf16)(v1.z*s); o[7]=(__bf16)(v1.w*s);
    } else {
#pragma unroll
        for (int q = 0; q < 8; q++) o[q] = (__bf16)0.f;
    }
    *(bf16x8*)(dst + (size_t)t8 * 8) = o;
}

// ---------------- M=32 MFMA GEMM (bf16 A, row-major bf16 out, B-dbuf) ----------------
template<int KDIM, int NTILES, int CSTRIDE>
__global__ __launch_bounds__(256) void gemm_k(
    const __bf16* __restrict__ Ap, const __bf16* __restrict__ Bp, __bf16* __restrict__ Cp,
    const float* __restrict__ bias)
{
    __shared__ __align__(16) __bf16 As[32][88];
    const int tid = threadIdx.x;
    const int w = tid >> 6, lane = tid & 63, c = lane & 15, quad = lane >> 4;
    const int mb = blockIdx.x, nb = blockIdx.y;
    constexpr int K32 = KDIM / 32;
    constexpr int NK  = KDIM / 64;
    constexpr int NT_W = NTILES / 2;
    const int wrow = w & 1, ncol0 = (w >> 1) * NT_W;

    f32x4 acc[NT_W];
#pragma unroll
    for (int nt = 0; nt < NT_W; nt++) acc[nt] = (f32x4){0.f, 0.f, 0.f, 0.f};

    const int row = tid >> 3, kp = (tid & 7) * 8;
    uint4 pb;
    auto issue  = [&](int kb) { pb = *(const uint4*)(Ap + (size_t)(mb * 32 + row) * KDIM + kb * 64 + kp); };
    auto commit = [&]() { *(uint4*)&As[row][kp] = pb; };

    bf16x8 bcur[2][NT_W], bnxt[2][NT_W];
    auto loadB = [&](int kb, bf16x8 (&dst)[2][NT_W]) {
#pragma unroll
        for (int kk = 0; kk < 2; kk++)
#pragma unroll
            for (int nt = 0; nt < NT_W; nt++)
                dst[kk][nt] = *(const bf16x8*)(Bp +
                    ((size_t)((nb * NTILES + ncol0 + nt) * K32 + kb * 2 + kk) * 64 + lane) * 8);
    };

    issue(0);
    loadB(0, bcur);
    for (int kb = 0; kb < NK; kb++) {
        commit();
        __syncthreads();
        if (kb + 1 < NK) { issue(kb + 1); loadB(kb + 1, bnxt); }
#pragma unroll
        for (int kk = 0; kk < 2; kk++) {
            bf16x8 a = *(const bf16x8*)&As[wrow * 16 + c][kk * 32 + quad * 8];
#pragma unroll
            for (int nt = 0; nt < NT_W; nt++)
                acc[nt] = __builtin_amdgcn_mfma_f32_16x16x32_bf16(a, bcur[kk][nt], acc[nt], 0, 0, 0);
        }
        if (kb + 1 < NK) {
#pragma unroll
            for (int kk = 0; kk < 2; kk++)
#pragma unroll
                for (int nt = 0; nt < NT_W; nt++) bcur[kk][nt] = bnxt[kk][nt];
        }
        __syncthreads();
    }

#pragma unroll
    for (int nt = 0; nt < NT_W; nt++) {
        int n = nb * (NTILES * 16) + (ncol0 + nt) * 16 + c;
        float bv = bias[n];
#pragma unroll
        for (int r0 = 0; r0 < 4; r0++) {
            int m = mb * 32 + wrow * 16 + quad * 4 + r0;
            Cp[(size_t)m * CSTRIDE + n] = (__bf16)(acc[nt][r0] + bv);
        }
    }
}

// ---------------- Git GEMM: M=64, transpose epilogue -> Git[dir][t][g][bh][d][b16] ----------------
__global__ __launch_bounds__(256) void gemm_git(
    const __bf16* __restrict__ Ap, const __bf16* __restrict__ Bp, __bf16* __restrict__ Cp,
    const float* __restrict__ bias)
{
    __shared__ __align__(16) __bf16 As[64][88];
    const int tid = threadIdx.x;
    const int w = tid >> 6, lane = tid & 63, c = lane & 15, quad = lane >> 4;
    const int mb = blockIdx.x, nb = blockIdx.y;   // grid (32, 24)

    f32x4 acc[4];
#pragma unroll
    for (int nt = 0; nt < 4; nt++) acc[nt] = (f32x4){0.f, 0.f, 0.f, 0.f};

    const int row = tid >> 2, kp = (tid & 3) * 16;
    uint4 pb[2];
    auto issue = [&](int kb) {
        const __bf16* ap = Ap + (size_t)(mb * 64 + row) * 256 + kb * 64 + kp;
        pb[0] = ((const uint4*)ap)[0]; pb[1] = ((const uint4*)ap)[1];
    };
    auto commit = [&]() {
        *(uint4*)&As[row][kp] = pb[0]; *(uint4*)&As[row][kp + 8] = pb[1];
    };

    bf16x8 bcur[2][4], bnxt[2][4];
    auto loadB = [&](int kb, bf16x8 (&dst)[2][4]) {
#pragma unroll
        for (int kk = 0; kk < 2; kk++)
#pragma unroll
            for (int nt = 0; nt < 4; nt++)
                dst[kk][nt] = *(const bf16x8*)(Bp +
                    ((size_t)((nb * 4 + nt) * 8 + kb * 2 + kk) * 64 + lane) * 8);
    };

    issue(0);
    loadB(0, bcur);
    for (int kb = 0; kb < 4; kb++) {
        commit();
        __syncthreads();
        if (kb + 1 < 4) { issue(kb + 1); loadB(kb + 1, bnxt); }
#pragma unroll
        for (int kk = 0; kk < 2; kk++) {
            bf16x8 a = *(const bf16x8*)&As[w * 16 + c][kk * 32 + quad * 8];
#pragma unroll
            for (int nt = 0; nt < 4; nt++)
                acc[nt] = __builtin_amdgcn_mfma_f32_16x16x32_bf16(a, bcur[kk][nt], acc[nt], 0, 0, 0);
        }
        if (kb + 1 < 4) {
#pragma unroll
            for (int kk = 0; kk < 2; kk++)
#pragma unroll
                for (int nt = 0; nt < 4; nt++) bcur[kk][nt] = bnxt[kk][nt];
        }
        __syncthreads();
    }

    // transpose: acc -> As[n_local][m_local], then coalesced b128 stores
#pragma unroll
    for (int nt = 0; nt < 4; nt++) {
        float bv = bias[nb * 64 + nt * 16 + c];
#pragma unroll
        for (int r0 = 0; r0 < 4; r0++)
            As[nt * 16 + c][w * 16 + quad * 4 + r0] = (__bf16)(acc[nt][r0] + bv);
    }
    __syncthreads();
    const int dd = tid >> 2, bch = tid & 3;
    const int n = nb * 64 + dd;
    const int dir = (n >= 768) ? 1 : 0;
    const int rem = n - dir * 768;
    const int g = rem >> 8, dcol = rem & 255;
#pragma unroll
    for (int tl = 0; tl < 2; tl++) {
        uint4 v = *(const uint4*)&As[dd][tl * 32 + bch * 8];
        size_t off = (size_t)dir * 1572864 + (size_t)(mb * 2 + tl) * 24576
                   + ((size_t)((g * 2 + (bch >> 1)) * 256 + dcol)) * 16 + (bch & 1) * 8;
        *(uint4*)(Cp + off) = v;
    }
}

// ---------------- recurrent GRU kernel (EXACT R5: measured best 118.5us) ----------------
__global__ __launch_bounds__(1024, 4) void gru_recurrent(
    const signed char* __restrict__ wq, const float* __restrict__ wscale,
    const float* __restrict__ bhh_r, const float* __restrict__ bhh_f,
    const __bf16* __restrict__ Git,
    __bf16* __restrict__ revb, __bf16* __restrict__ fwdb)
{
    __shared__ __align__(16) signed char hbuf[2][16][272];
    __shared__ __align__(16) __bf16 hist[8][4096];
    const int tid = threadIdx.x;
    const int w = tid >> 6, lane = tid & 63, c = lane & 15, quad = lane >> 4;
    const int bid = blockIdx.x;
    const bool isF = (bid < 2);
    const int ia = isF ? 63 : (63 - ((bid - 2) >> 1));
    const int bh = bid & 1;
    const int b0 = bh << 4;
    const int steps = ia + 1;
    const float* bhh = isF ? bhh_f : bhh_r;
    __bf16* outb = isF ? fwdb : (revb + ((size_t)(ia * (ia + 1) / 2)) * 8192);

    const int4v* pw = (const int4v*)(wq + (isF ? 196608 : 0));
    int4v bw[3][4];
#pragma unroll
    for (int g = 0; g < 3; g++)
#pragma unroll
        for (int ks = 0; ks < 4; ks++)
            bw[g][ks] = pw[(size_t)((g * 16 + w) * 4 + ks) * 64 + lane];
    const int d = (w << 4) + c;
    float sc[3];
#pragma unroll
    for (int g = 0; g < 3; g++) sc[g] = wscale[(isF ? 768 : 0) + g * 256 + d];
    const float bnv = bhh[512 + d] * TWO_L2E;

    float hreg[4] = {0.f, 0.f, 0.f, 0.f};
    for (int idx = tid; idx < 2 * 16 * 272 / 4; idx += 1024) ((int*)hbuf)[idx] = 0;
    __syncthreads();

    // Git[dir][t][g][bh][d][b16]: per-(wave,g) loads are 512B contiguous.
    const __bf16* gb = Git + (size_t)(isF ? 64 : ia) * 24576;
    const long gstep = isF ? 24576 : -24576;
    int loff[3];
#pragma unroll
    for (int g = 0; g < 3; g++) loff[g] = ((g * 2 + bh) * 256 + d) * 16 + (quad << 2);

    auto flush = [&](int jbase, int cnt) {
        int s = tid >> 7;
        if (s < cnt) {
            const uint4* src = (const uint4*)((const char*)&hist[s][0] + (tid & 127) * 64);
            uint4 v0 = src[0], v1 = src[1], v2 = src[2], v3 = src[3];
            uint4* dst = (uint4*)(outb + (size_t)(jbase + s) * 8192 + b0 * 256 + (tid & 127) * 32);
            dst[0] = v0; dst[1] = v1; dst[2] = v2; dst[3] = v3;
        }
    };

    bf16x4 gcur[3], gnxt[3];
#pragma unroll
    for (int g = 0; g < 3; g++) gcur[g] = *(const bf16x4*)(gb + loff[g]);

    for (int j = 0; j < steps; j++) {
        const int rb = j & 1, wbuf = rb ^ 1;

        if (j + 1 < steps) {
            const __bf16* gn = gb + gstep;
#pragma unroll
            for (int g = 0; g < 3; g++) gnxt[g] = *(const bf16x4*)(gn + loff[g]);
        }

        int4v a0 = {0,0,0,0}, a1 = {0,0,0,0}, a2 = {0,0,0,0};
#pragma unroll
        for (int ks = 0; ks < 4; ks++) {
            int4v av = *(const int4v*)&hbuf[rb][c][ks * 64 + (quad << 4)];
            a0 = __builtin_amdgcn_mfma_i32_16x16x64_i8(av, bw[0][ks], a0, 0, 0, 0);
            a1 = __builtin_amdgcn_mfma_i32_16x16x64_i8(av, bw[1][ks], a1, 0, 0, 0);
            a2 = __builtin_amdgcn_mfma_i32_16x16x64_i8(av, bw[2][ks], a2, 0, 0, 0);
        }

        const int hs = j & 7;
#pragma unroll
        for (int r0 = 0; r0 < 4; r0++) {
            float er = __builtin_amdgcn_exp2f(fmaf((float)a0[r0], sc[0], (float)gcur[0][r0]));
            float rg = __builtin_amdgcn_rcpf(1.f + er);
            float ez = __builtin_amdgcn_exp2f(fmaf((float)a1[r0], sc[1], (float)gcur[1][r0]));
            float zg = __builtin_amdgcn_rcpf(1.f + ez);
            float narg = fmaf(rg, fmaf((float)a2[r0], sc[2], bnv), (float)gcur[2][r0]);
            float en = __builtin_amdgcn_exp2f(narg);
            float ng = fmaf(-2.f, __builtin_amdgcn_rcpf(1.f + en), 1.f);
            float h  = fmaf(zg, hreg[r0] - ng, ng);
            hreg[r0] = h;
            int row = (quad << 2) + r0;
            hbuf[wbuf][row][d] = (signed char)(int)__builtin_rintf(h * 127.f);
            hist[hs][row * 256 + d] = (__bf16)h;
        }
        LDS_BARRIER();
        if (hs == 7) {                     // batched flush: stores off the per-step FIFO path
            flush(j - 7, 8);
            LDS_BARRIER();
        }
        gb += gstep;
#pragma unroll
        for (int g = 0; g < 3; g++) gcur[g] = gnxt[g];
    }
    int rem = steps & 7;
    if (rem) flush(steps - rem, rem);
}

// ---------------- attention (online softmax over t<=i) ----------------
__global__ __launch_bounds__(512) void attn_kernel(
    const __bf16* __restrict__ revb, const __bf16* __restrict__ fwdb,
    const float* __restrict__ attn_w, const float* __restrict__ attn_bp,
    __bf16* __restrict__ ht)
{
    const int tid = threadIdx.x;
    const int w = tid >> 6, lane = tid & 63;
    const int wid = blockIdx.x * 8 + w;      // 2048 waves: one per (i,b)
    const int i = wid >> 5, b = wid & 31;
    const int d0 = lane * 4;

    float wf[4], wr[4];
#pragma unroll
    for (int q = 0; q < 4; q++) { wf[q] = attn_w[d0 + q]; wr[q] = attn_w[256 + d0 + q]; }
    const float ab = attn_bp[0];
    const __bf16* rp = revb + ((size_t)(i * (i + 1) / 2)) * 8192 + (size_t)b * 256 + d0;
    const __bf16* fp = fwdb + (size_t)b * 256 + d0;

    float mx = -1e30f, l = 0.f;
    float cf[4] = {0,0,0,0}, cr[4] = {0,0,0,0};
    bf16x4 rn = *(const bf16x4*)rp, fn = *(const bf16x4*)fp;
    for (int t = 0; t <= i; t++) {
        bf16x4 rv4 = rn, fv4 = fn;
        if (t < i) {
            rn = *(const bf16x4*)(rp + (size_t)(t + 1) * 8192);
            fn = *(const bf16x4*)(fp + (size_t)(t + 1) * 8192);
        }
        float rv[4], fv[4], s = 0.f;
#pragma unroll
        for (int q = 0; q < 4; q++) {
            rv[q] = (float)rv4[q]; fv[q] = (float)fv4[q];
            s += rv[q] * wr[q] + fv[q] * wf[q];
        }
#pragma unroll
        for (int off = 32; off > 0; off >>= 1) s += __shfl_xor(s, off);
        s += ab;
        float mn = fmaxf(mx, s);
        float scl = __expf(mx - mn);
        float p  = __expf(s - mn);
        l = l * scl + p;
#pragma unroll
        for (int q = 0; q < 4; q++) { cf[q] = cf[q] * scl + p * fv[q]; cr[q] = cr[q] * scl + p * rv[q]; }
        mx = mn;
    }
    float inv = __builtin_amdgcn_rcpf(l * (float)(i + 1));
    __bf16* hp = ht + (size_t)(i * 32 + b) * 1024 + d0;
    const __bf16* fl = fp + (size_t)i * 8192;
    const __bf16* rl = rp + (size_t)i * 8192;
#pragma unroll
    for (int q = 0; q < 4; q++) {
        hp[q]       = (__bf16)(cf[q] * inv);
        hp[256 + q] = (__bf16)(cr[q] * inv);
        hp[512 + q] = fl[q];
        hp[768 + q] = rl[q];
    }
}

// ---------------- fused head: out = sigmoid((ht@Wao^T+bao)@Wo^T+bo) ----------------
// grid 64 x 256 thr. Phase 1: t1[32x256] into LDS; phase 2: K=256 GEMM from LDS + sigmoid.
__global__ __launch_bounds__(256, 1) void head_fused(
    const __bf16* __restrict__ ht, const __bf16* __restrict__ Bao, const float* __restrict__ bao,
    const __bf16* __restrict__ Bo, const float* __restrict__ bo, float* __restrict__ out)
{
    __shared__ __align__(16) __bf16 As[32][88];
    __shared__ __align__(16) __bf16 tmp[32][264];
    const int tid = threadIdx.x;
    const int w = tid >> 6, lane = tid & 63, c = lane & 15, quad = lane >> 4;
    const int mb = blockIdx.x;

    // ---- phase 1: t1 = ht[32 rows] @ Wao^T + bao (K=1024, N=256) ----
    const int wrow = w & 1, colg = w >> 1;
    f32x4 acc1[8];
#pragma unroll
    for (int nt = 0; nt < 8; nt++) acc1[nt] = (f32x4){0.f, 0.f, 0.f, 0.f};
    const int row = tid >> 3, kp = (tid & 7) * 8;
    uint4 pb;
    auto issue  = [&](int kb) { pb = *(const uint4*)(ht + (size_t)(mb * 32 + row) * 1024 + kb * 64 + kp); };
    auto commit = [&]() { *(uint4*)&As[row][kp] = pb; };

    issue(0);
    for (int kb = 0; kb < 16; kb++) {
        commit();
        __syncthreads();
        if (kb + 1 < 16) issue(kb + 1);
#pragma unroll
        for (int kk = 0; kk < 2; kk++) {
            bf16x8 a = *(const bf16x8*)&As[wrow * 16 + c][kk * 32 + quad * 8];
#pragma unroll
            for (int nt = 0; nt < 8; nt++) {
                bf16x8 bfr = *(const bf16x8*)(Bao +
                    ((size_t)((colg * 8 + nt) * 32 + kb * 2 + kk) * 64 + lane) * 8);
                acc1[nt] = __builtin_amdgcn_mfma_f32_16x16x32_bf16(a, bfr, acc1[nt], 0, 0, 0);
            }
        }
        __syncthreads();
    }
#pragma unroll
    for (int nt = 0; nt < 8; nt++) {
        int n = colg * 128 + nt * 16 + c;
        float bv = bao[n];
#pragma unroll
        for (int r0 = 0; r0 < 4; r0++)
            tmp[wrow * 16 + quad * 4 + r0][n] = (__bf16)(acc1[nt][r0] + bv);
    }
    __syncthreads();

    // ---- phase 2: out = sigmoid(t1 @ Wo^T + bo) (K=256, N=942; wave w: col-tiles w*15..+14) ----
    f32x4 acc2[2][15];
#pragma unroll
    for (int rt = 0; rt < 2; rt++)
#pragma unroll
        for (int nt = 0; nt < 15; nt++) acc2[rt][nt] = (f32x4){0.f, 0.f, 0.f, 0.f};
#pragma unroll
    for (int kb = 0; kb < 4; kb++) {
#pragma unroll
        for (int kk = 0; kk < 2; kk++) {
            bf16x8 a0 = *(const bf16x8*)&tmp[c][kb * 64 + kk * 32 + quad * 8];
            bf16x8 a1 = *(const bf16x8*)&tmp[16 + c][kb * 64 + kk * 32 + quad * 8];
#pragma unroll
            for (int nt = 0; nt < 15; nt++) {
                bf16x8 bfr = *(const bf16x8*)(Bo +
                    ((size_t)((w * 15 + nt) * 8 + kb * 2 + kk) * 64 + lane) * 8);
                acc2[0][nt] = __builtin_amdgcn_mfma_f32_16x16x32_bf16(a0, bfr, acc2[0][nt], 0, 0, 0);
                acc2[1][nt] = __builtin_amdgcn_mfma_f32_16x16x32_bf16(a1, bfr, acc2[1][nt], 0, 0, 0);
            }
        }
    }
#pragma unroll
    for (int nt = 0; nt < 15; nt++) {
        int n = (w * 15 + nt) * 16 + c;
        if (n < 942) {
            float bv = bo[n];
#pragma unroll
            for (int rt = 0; rt < 2; rt++)
#pragma unroll
                for (int r0 = 0; r0 < 4; r0++) {
                    int m = mb * 32 + rt * 16 + quad * 4 + r0;
                    out[(size_t)m * 942 + n] = sigf(acc2[rt][nt][r0] + bv);
                }
        }
    }
}

// ---------------- launch ----------------
extern "C" void kernel_launch(void* const* d_in, const int* in_sizes, int n_in,
                              void* d_out, int out_size, void* d_ws, size_t ws_size,
                              hipStream_t stream) {
    const float* x      = (const float*)d_in[0];
    const float* W_emb  = (const float*)d_in[1];
    const float* b_emb  = (const float*)d_in[2];
    const float* Wih_f  = (const float*)d_in[3];
    const float* Whh_f  = (const float*)d_in[4];
    const float* bih_f  = (const float*)d_in[5];
    const float* bhh_f  = (const float*)d_in[6];
    const float* Wih_r  = (const float*)d_in[7];
    const float* Whh_r  = (const float*)d_in[8];
    const float* bih_r  = (const float*)d_in[9];
    const float* bhh_r  = (const float*)d_in[10];
    const float* attn_w = (const float*)d_in[11];
    const float* attn_b = (const float*)d_in[12];
    const float* W_ao   = (const float*)d_in[13];
    const float* b_ao   = (const float*)d_in[14];
    const float* W_o    = (const float*)d_in[15];
    const float* b_o    = (const float*)d_in[16];
    float* out = (float*)d_out;

    char* ws = (char*)d_ws;
    __bf16* pk_emb = (__bf16*)(ws + OFF_PK_EMB);
    __bf16* pk_ih  = (__bf16*)(ws + OFF_PK_IH);
    signed char* wq = (signed char*)(ws + OFF_WQ);
    float*  wsc    = (float*)(ws + OFF_WSC);
    __bf16* pk_ao  = (__bf16*)(ws + OFF_PK_AO);
    __bf16* pk_o   = (__bf16*)(ws + OFF_PK_O);
    __bf16* day    = (__bf16*)(ws + OFF_DAY);
    __bf16* Git    = (__bf16*)(ws + OFF_GIT);
    float*  bc     = (float*)(ws + OFF_BC);
    __bf16* revb   = (__bf16*)(ws + OFF_REV);
    __bf16* fwdb   = (__bf16*)(ws + OFF_FWD);
    __bf16* ht     = (__bf16*)(ws + OFF_HT);
    __bf16* xb     = (__bf16*)(ws + OFF_XB);     // aliases revb (dead until gru)

    pack_misc<<<5432, 256, 0, stream>>>(W_emb, Wih_r, Wih_f, W_ao, W_o, x,
                                        Whh_r, Whh_f, bih_r, bih_f, bhh_r, bhh_f,
                                        pk_emb, pk_ih, pk_ao, pk_o, xb, wq, wsc, bc);

    gemm_k<4096, 4, 256><<<dim3(64, 4), 256, 0, stream>>>(xb, pk_emb, day, b_emb);
    gemm_git<<<dim3(32, 24), 256, 0, stream>>>(day, pk_ih, Git, bc);

    gru_recurrent<<<130, 1024, 0, stream>>>(wq, wsc, bhh_r, bhh_f, Git, revb, fwdb);

    attn_kernel<<<256, 512, 0, stream>>>(revb, fwdb, attn_w, attn_b, ht);

    head_fused<<<64, 256, 0, stream>>>(ht, pk_ao, b_ao, pk_o, b_o, out);
}